// Round 5
// baseline (850.533 us; speedup 1.0000x reference)
//
#include <hip/hip_runtime.h>

// ---------- types ----------
typedef short v8s __attribute__((ext_vector_type(8)));
typedef float v4f __attribute__((ext_vector_type(4)));
typedef unsigned int v4u __attribute__((ext_vector_type(4)));
typedef unsigned long long u64;

static __device__ __forceinline__ unsigned short f2bf(float x) {
    unsigned u = __builtin_bit_cast(unsigned, x);
    unsigned r = (u + 0x7fffu + ((u >> 16) & 1u)) >> 16;
    return (unsigned short)r;
}

static __device__ __forceinline__ float sigm(float x) {
    return 1.f / (1.f + __expf(-x));
}
static __device__ __forceinline__ float tanh_fast(float x) {
    x = fminf(fmaxf(x, -15.f), 15.f);
    float e = __expf(2.f * x);
    return (e - 1.f) / (e + 1.f);
}

// ---------- elementwise f32 -> bf16 convert ----------
__global__ void cvt_bf16(const float* __restrict__ src, unsigned short* __restrict__ dst, int n) {
    int i = blockIdx.x * 256 + threadIdx.x;
    if (i < n) dst[i] = f2bf(src[i]);
}

// ---------- repack W_hh (f32 [1536][512]) into MFMA B-fragment order ----------
// dst: [96 tiles][16 kf][64 lane][8 i] bf16, per dir.
__global__ void repack_whh(const float* __restrict__ src, unsigned short* __restrict__ dst) {
    long e = (long)blockIdx.x * 256 + threadIdx.x;  // < 786432
    int i = e & 7;
    int lane = (e >> 3) & 63;
    int kf = (e >> 9) & 15;
    int T = (int)(e >> 13);  // 0..95
    int gcol = T * 16 + (lane & 15);
    int k = kf * 32 + (lane >> 4) * 8 + i;
    dst[e] = f2bf(src[(long)gcol * 512 + k]);
}

// ---------- zero team flags (every launch, incl. graph replays) ----------
// 16 teams x 64 per-wave flags = 1024 dwords
__global__ void init_flags(unsigned int* __restrict__ p) {
    p[blockIdx.x * 256 + threadIdx.x] = 0;
}

// ---------- build X = concat(embed_table[slot_ids], value_embeds) as bf16 [16384][1024] ----------
__global__ void build_x(const int* __restrict__ slot_ids,
                        const float* __restrict__ value_embeds,
                        const float* __restrict__ embed_table,
                        unsigned short* __restrict__ X) {
    int r = blockIdx.x;           // r = b*64 + s
    int t = threadIdx.x;          // 256 threads
    int id = slot_ids[r];
    X[(long)r * 1024 + t] = f2bf(embed_table[id * 256 + t]);
#pragma unroll
    for (int i = 0; i < 3; i++) {
        int c = t + i * 256;
        X[(long)r * 1024 + 256 + c] = f2bf(value_embeds[(long)r * 768 + c]);
    }
}

// ---------- bf16 MFMA GEMM: C[M][N] = A[M][K] * Bt[N][K]^T ----------
// EPI=0: plain f32 store C[row*N+col]
// EPI=1: scatter gi packed for gru_rec consumers:
//   [d][s][bg 8][cb 16][wave 4][g 3][lane 64][r 4] f32
template <int EPI>
__global__ __launch_bounds__(256) void gemm_bt(const unsigned short* __restrict__ A,
                                               const unsigned short* __restrict__ Bt,
                                               float* __restrict__ C,
                                               int M, int N, int K) {
    const int LDT = 72;
    __shared__ unsigned short As[128 * 72];
    __shared__ unsigned short Bs[128 * 72];
    int tid = threadIdx.x;
    int lane = tid & 63;
    int wave = tid >> 6;
    int gm0 = blockIdx.y * 128;
    int gn0 = blockIdx.x * 128;
    int wm0 = (wave >> 1) * 64;
    int wn0 = (wave & 1) * 64;
    int q = lane >> 4;
    int l16 = lane & 15;

    v4f acc[4][4];
#pragma unroll
    for (int i = 0; i < 4; i++)
#pragma unroll
        for (int j = 0; j < 4; j++) acc[i][j] = v4f{0.f, 0.f, 0.f, 0.f};

    for (int k0 = 0; k0 < K; k0 += 64) {
#pragma unroll
        for (int l = tid; l < 1024; l += 256) {
            int row = l >> 3;
            int col = (l & 7) * 8;
            *(v8s*)&As[row * LDT + col] = *(const v8s*)&A[(long)(gm0 + row) * K + k0 + col];
            *(v8s*)&Bs[row * LDT + col] = *(const v8s*)&Bt[(long)(gn0 + row) * K + k0 + col];
        }
        __syncthreads();
#pragma unroll
        for (int kf = 0; kf < 2; kf++) {
            v8s af[4], bfr[4];
#pragma unroll
            for (int mi = 0; mi < 4; mi++)
                af[mi] = *(const v8s*)&As[(wm0 + mi * 16 + l16) * LDT + kf * 32 + q * 8];
#pragma unroll
            for (int ni = 0; ni < 4; ni++)
                bfr[ni] = *(const v8s*)&Bs[(wn0 + ni * 16 + l16) * LDT + kf * 32 + q * 8];
#pragma unroll
            for (int mi = 0; mi < 4; mi++)
#pragma unroll
                for (int ni = 0; ni < 4; ni++)
                    acc[mi][ni] = __builtin_amdgcn_mfma_f32_16x16x32_bf16(af[mi], bfr[ni], acc[mi][ni], 0, 0, 0);
        }
        __syncthreads();
    }

#pragma unroll
    for (int mi = 0; mi < 4; mi++)
#pragma unroll
        for (int ni = 0; ni < 4; ni++) {
            int col = gn0 + wn0 + ni * 16 + l16;
#pragma unroll
            for (int r = 0; r < 4; r++) {
                int row = gm0 + wm0 + mi * 16 + q * 4 + r;
                float v = acc[mi][ni][r];
                if (EPI == 0) {
                    C[(long)row * N + col] = v;
                } else {
                    int dd = (col >= 1536) ? 1 : 0;
                    int gcol = col - dd * 1536;
                    int g = gcol >> 9;
                    int jj = gcol & 511;
                    int cb = jj >> 5;
                    int jc = jj & 31;
                    int jhc = jc >> 4;
                    int l16c = jc & 15;
                    int b = row >> 6, s = row & 63;
                    int bg = b >> 5, brow = b & 31;
                    int rgc = brow >> 4, m = brow & 15;
                    int qc = m >> 2, rc = m & 3;
                    int wv = rgc * 2 + jhc;
                    long idx = (((((long)(dd * 64 + s) * 8 + bg) * 16 + cb) * 4 + wv) * 3 + g) * 256 +
                               (qc * 16 + l16c) * 4 + rc;
                    C[idx] = v;
                }
            }
        }
}

// ---------- GRU recurrence: W in AGPRs, per-wave flags, no LDS, no barriers ----------
// 256 blocks x 256 threads (1 block/CU). blk = d*128 + bg*16 + cb.
// team = (d,bg): 16 blocks x 4 waves = 64 producer waves splitting 512 h-cols.
// DECISIVE FIX THIS ROUND: rounds 1-4 all showed VGPR_Count ~136-164 < 192 = sizeof(bfr)
// -> the compiler NEVER kept W_hh resident; it re-fetched 48 B-fragments (48KB/wave)
// from L2/scratch inside the MFMA loop EVERY step (~150GB/s per-CU L1 path ~= 1.3-3us/step,
// latency-serialized with dependent MFMAs). The "+v" pin (round 4) only forces residency
// at the pin point, not through the loop. Now each fragment is held as v4u, pinned into
// the AGPR file via asm("" : "+a") and consumed by inline-asm MFMA with an "a" B-operand
// (gfx950 MFMA reads B directly from AGPRs, ISA sec 10) — AGPR-held values cannot be
// rematerialized or demoted. Budget: 192 AGPR + ~150 VGPR < 512 unified @ 1 wave/SIMD.
// Sync protocol = round 3 exactly (best so far): sc1 data stores -> vmcnt(0) -> relaxed
// per-wave flag; consumer polls 64 flags (one vector load/iter) then 16-in-flight
// early-clobber asm loads. hout stores + gi prefetch after the flag, off the chain.
__global__ __launch_bounds__(256, 1) void gru_rec(const float* __restrict__ gi,           // packed, see EPI=1
                                                  const unsigned short* __restrict__ Wpk, // [2][96][16][64][8]
                                                  const float* __restrict__ bih_f,
                                                  const float* __restrict__ bhh_f,
                                                  const float* __restrict__ bih_b,
                                                  const float* __restrict__ bhh_b,
                                                  unsigned short* __restrict__ hout,      // [256][64][1024]
                                                  unsigned int* __restrict__ hshd,        // [16][2][8192] dwords
                                                  unsigned int* __restrict__ flags) {     // [16][64]
    int tid = threadIdx.x;
    int lane = tid & 63;
    int wave = tid >> 6;          // 0..3
    int q = lane >> 4, l16 = lane & 15;
    int blk = blockIdx.x;
    int d = blk >> 7;
    int bg = (blk >> 4) & 7;
    int cb = blk & 15;
    int team = d * 8 + bg;
    int rg = wave >> 1, jh = wave & 1;
    int j = cb * 32 + jh * 16 + l16;   // owned h-col

    // W_hh B-fragments (step-invariant): 3 gates x 16 kf, each 4 regs -> 192 AGPRs.
    v4u wA[3][16];
#pragma unroll
    for (int g = 0; g < 3; g++) {
        const unsigned short* wp = Wpk + ((long)d * 96 + (g * 32 + cb * 2 + jh)) * 8192;
#pragma unroll
        for (int kf = 0; kf < 16; kf++) {
            v8s w = *(const v8s*)&wp[(kf * 64 + lane) * 8];
            wA[g][kf] = __builtin_bit_cast(v4u, w);
            // Force into the AGPR file; an AGPR-held value cannot be demoted/remat'd.
            asm volatile("" : "+a"(wA[g][kf]));
        }
    }

    float bi[3], bh[3];
    {
        const float* bihp = d ? bih_b : bih_f;
        const float* bhhp = d ? bhh_b : bhh_f;
#pragma unroll
        for (int g = 0; g < 3; g++) {
            bi[g] = bihp[g * 512 + j];
            bh[g] = bhhp[g * 512 + j];
        }
    }
    float hreg[4] = {0.f, 0.f, 0.f, 0.f};

    unsigned int* myflags = flags + team * 64;
    unsigned int* hsteam = hshd + (long)team * 2 * 8192;

    // prefetch gi for t = 0
    v4f gir[3];
    {
        int s0 = d ? 63 : 0;
        const float* gp = gi + (((((long)(d * 64 + s0)) * 8 + bg) * 16 + cb) * 4 + wave) * 768 + lane * 4;
#pragma unroll
        for (int g = 0; g < 3; g++) gir[g] = __builtin_nontemporal_load((const v4f*)(gp + g * 256));
    }

    for (int t = 0; t < 64; t++) {
        int s = d ? (63 - t) : t;

        v4f acc[3];
#pragma unroll
        for (int g = 0; g < 3; g++) acc[g] = v4f{0.f, 0.f, 0.f, 0.f};

        if (t > 0) {
            // per-wave poll: all 64 producer-wave flags of this team must reach t
            while (__hip_atomic_load(&myflags[lane], __ATOMIC_RELAXED, __HIP_MEMORY_SCOPE_AGENT) <
                   (unsigned)t)
                __builtin_amdgcn_s_sleep(1);
            __builtin_amdgcn_sched_barrier(0);

            // h_{t-1} A-fragments straight from the exchange buffer (row-major [32][512] bf16).
            // 16 device-scope (sc1) 16B loads off one base, all in flight. EARLY-CLOBBER
            // outputs (round 2's crash: without & the dst may alias the address pair).
            const char* hb = (const char*)hsteam + ((t + 1) & 1) * 32768 +
                             (rg * 16 + l16) * 1024 + q * 16;
            v4u a0, a1, a2, a3, a4, a5, a6, a7, a8, a9, a10, a11, a12, a13, a14, a15;
            asm volatile(
                "global_load_dwordx4 %0, %16, off sc1\n\t"
                "global_load_dwordx4 %1, %16, off offset:64 sc1\n\t"
                "global_load_dwordx4 %2, %16, off offset:128 sc1\n\t"
                "global_load_dwordx4 %3, %16, off offset:192 sc1\n\t"
                "global_load_dwordx4 %4, %16, off offset:256 sc1\n\t"
                "global_load_dwordx4 %5, %16, off offset:320 sc1\n\t"
                "global_load_dwordx4 %6, %16, off offset:384 sc1\n\t"
                "global_load_dwordx4 %7, %16, off offset:448 sc1\n\t"
                "global_load_dwordx4 %8, %16, off offset:512 sc1\n\t"
                "global_load_dwordx4 %9, %16, off offset:576 sc1\n\t"
                "global_load_dwordx4 %10, %16, off offset:640 sc1\n\t"
                "global_load_dwordx4 %11, %16, off offset:704 sc1\n\t"
                "global_load_dwordx4 %12, %16, off offset:768 sc1\n\t"
                "global_load_dwordx4 %13, %16, off offset:832 sc1\n\t"
                "global_load_dwordx4 %14, %16, off offset:896 sc1\n\t"
                "global_load_dwordx4 %15, %16, off offset:960 sc1"
                : "=&v"(a0), "=&v"(a1), "=&v"(a2), "=&v"(a3), "=&v"(a4), "=&v"(a5), "=&v"(a6),
                  "=&v"(a7), "=&v"(a8), "=&v"(a9), "=&v"(a10), "=&v"(a11), "=&v"(a12), "=&v"(a13),
                  "=&v"(a14), "=&v"(a15)
                : "v"(hb)
                : "memory");
            asm volatile("s_waitcnt vmcnt(0)" ::: "memory");
            __builtin_amdgcn_sched_barrier(0);

            v4u af[16];
            af[0] = a0;  af[1] = a1;  af[2] = a2;  af[3] = a3;
            af[4] = a4;  af[5] = a5;  af[6] = a6;  af[7] = a7;
            af[8] = a8;  af[9] = a9;  af[10] = a10; af[11] = a11;
            af[12] = a12; af[13] = a13; af[14] = a14; af[15] = a15;

            // 48 MFMA, B operand sourced DIRECTLY from AGPRs (no per-use reload possible).
#pragma unroll
            for (int kf = 0; kf < 16; kf++)
#pragma unroll
                for (int g = 0; g < 3; g++)
                    asm("v_mfma_f32_16x16x32_bf16 %0, %1, %2, %0"
                        : "+v"(acc[g])
                        : "v"(af[kf]), "a"(wA[g][kf]));
        }

        // combine gates, update h, publish exchange slice (sc1 dword stores)
        unsigned int* dst = hsteam + (t & 1) * 8192;
        unsigned short hv[4];
#pragma unroll
        for (int r = 0; r < 4; r++) {
            float rr = sigm(gir[0][r] + bi[0] + acc[0][r] + bh[0]);
            float zz = sigm(gir[1][r] + bi[1] + acc[1][r] + bh[1]);
            float nn = tanh_fast(gir[2][r] + bi[2] + rr * (acc[2][r] + bh[2]));
            float hn = (1.f - zz) * nn + zz * hreg[r];
            hreg[r] = hn;
            hv[r] = f2bf(hn);
            float pv = __shfl_xor(hn, 1);
            if ((l16 & 1) == 0) {
                unsigned int pack = (unsigned int)hv[r] | ((unsigned int)f2bf(pv) << 16);
                int row = rg * 16 + q * 4 + r;
                __hip_atomic_store(&dst[row * 256 + (j >> 1)], pack, __ATOMIC_RELAXED,
                                   __HIP_MEMORY_SCOPE_AGENT);
            }
        }

        // drain this wave's sc1 stores to the coherence point, then publish per-wave flag
        asm volatile("s_waitcnt vmcnt(0)" ::: "memory");
        if (lane == 0)
            __hip_atomic_store(&myflags[cb * 4 + wave], (unsigned)(t + 1), __ATOMIC_RELAXED,
                               __HIP_MEMORY_SCOPE_AGENT);

        // off the critical path: final output + next-step gi prefetch
#pragma unroll
        for (int r = 0; r < 4; r++) {
            int row = rg * 16 + q * 4 + r;
            hout[((long)(bg * 32 + row) * 64 + s) * 1024 + d * 512 + j] = hv[r];
        }
        if (t < 63) {
            int sn = d ? (62 - t) : (t + 1);
            const float* gp =
                gi + (((((long)(d * 64 + sn)) * 8 + bg) * 16 + cb) * 4 + wave) * 768 + lane * 4;
#pragma unroll
            for (int g = 0; g < 3; g++) gir[g] = __builtin_nontemporal_load((const v4f*)(gp + g * 256));
        }
    }
}

extern "C" void kernel_launch(void* const* d_in, const int* in_sizes, int n_in,
                              void* d_out, int out_size, void* d_ws, size_t ws_size,
                              hipStream_t stream) {
    const int* slot_ids = (const int*)d_in[0];
    const float* value_embeds = (const float*)d_in[1];
    const float* embed_table = (const float*)d_in[2];
    const float* W_ih_f = (const float*)d_in[3];
    const float* W_hh_f = (const float*)d_in[4];
    const float* b_ih_f = (const float*)d_in[5];
    const float* b_hh_f = (const float*)d_in[6];
    const float* W_ih_b = (const float*)d_in[7];
    const float* W_hh_b = (const float*)d_in[8];
    const float* b_ih_b = (const float*)d_in[9];
    const float* b_hh_b = (const float*)d_in[10];
    const float* W_proj = (const float*)d_in[11];
    float* out = (float*)d_out;
    char* ws = (char*)d_ws;

    // workspace layout (bytes)
    unsigned short* X = (unsigned short*)(ws + 0);              // 16384x1024 bf16 = 33,554,432
    float* gi = (float*)(ws + 33554432);                        // 50,331,648 f32 = 201,326,592
    unsigned short* Wstk = (unsigned short*)(ws + 234881024);   // 3072x1024 bf16 = 6,291,456 (dead after gemm1)
    unsigned short* Wpk = (unsigned short*)(ws + 241172480);    // 2x96x16x64x8 bf16 = 3,145,728
    unsigned short* Wp = (unsigned short*)(ws + 244318208);     // 512x1024 bf16 = 1,048,576
    unsigned short* hout = X;  // alias: X dead after gemm1
    // h-share + flags alias the (dead-after-gemm1) Wstk region
    unsigned int* hshd = (unsigned int*)Wstk;                   // 16*2*8192 dwords = 1 MB
    unsigned int* flags = (unsigned int*)(ws + 234881024 + 1048576);  // 1024 dwords

    cvt_bf16<<<6144, 256, 0, stream>>>(W_ih_f, Wstk, 1536 * 1024);
    cvt_bf16<<<6144, 256, 0, stream>>>(W_ih_b, Wstk + 1536 * 1024, 1536 * 1024);
    repack_whh<<<3072, 256, 0, stream>>>(W_hh_f, Wpk);
    repack_whh<<<3072, 256, 0, stream>>>(W_hh_b, Wpk + 786432);
    cvt_bf16<<<2048, 256, 0, stream>>>(W_proj, Wp, 512 * 1024);
    build_x<<<16384, 256, 0, stream>>>(slot_ids, value_embeds, embed_table, X);

    // gi = X @ [Wih_f; Wih_b]^T  (M=16384, N=3072, K=1024), packed epilogue
    gemm_bt<1><<<dim3(24, 128), 256, 0, stream>>>(X, Wstk, gi, 16384, 3072, 1024);

    // zero flags (after gemm1: aliases Wstk region)
    init_flags<<<4, 256, 0, stream>>>(flags);

    // recurrence: 256 co-resident blocks, AGPR-resident W, per-wave flag sync
    gru_rec<<<256, 256, 0, stream>>>(gi, Wpk, b_ih_f, b_hh_f, b_ih_b, b_hh_b, hout, hshd, flags);

    // out = hcat @ W_proj^T   (M=16384, N=512, K=1024)
    gemm_bt<0><<<dim3(4, 128), 256, 0, stream>>>(hout, Wp, out, 16384, 512, 1024);
}

// Round 10
// 835.798 us; speedup vs baseline: 1.0176x; 1.0176x over previous
//
#include <hip/hip_runtime.h>

// ---------- types ----------
typedef short v8s __attribute__((ext_vector_type(8)));
typedef float v4f __attribute__((ext_vector_type(4)));
typedef unsigned int v4u __attribute__((ext_vector_type(4)));

static __device__ __forceinline__ unsigned short f2bf(float x) {
    unsigned u = __builtin_bit_cast(unsigned, x);
    unsigned r = (u + 0x7fffu + ((u >> 16) & 1u)) >> 16;
    return (unsigned short)r;
}

static __device__ __forceinline__ float sigm(float x) {
    return 1.f / (1.f + __expf(-x));
}
static __device__ __forceinline__ float tanh_fast(float x) {
    x = fminf(fmaxf(x, -15.f), 15.f);
    float e = __expf(2.f * x);
    return (e - 1.f) / (e + 1.f);
}

// ---------- elementwise f32 -> bf16 convert ----------
__global__ void cvt_bf16(const float* __restrict__ src, unsigned short* __restrict__ dst, int n) {
    int i = blockIdx.x * 256 + threadIdx.x;
    if (i < n) dst[i] = f2bf(src[i]);
}

// ---------- repack W_hh (f32 [1536][512]) into MFMA B-fragment order ----------
__global__ void repack_whh(const float* __restrict__ src, unsigned short* __restrict__ dst) {
    long e = (long)blockIdx.x * 256 + threadIdx.x;  // < 786432
    int i = e & 7;
    int lane = (e >> 3) & 63;
    int kf = (e >> 9) & 15;
    int T = (int)(e >> 13);  // 0..95
    int gcol = T * 16 + (lane & 15);
    int k = kf * 32 + (lane >> 4) * 8 + i;
    dst[e] = f2bf(src[(long)gcol * 512 + k]);
}

// ---------- zero team flags (every launch, incl. graph replays) ----------
// 16 teams x 64 per-wave flags = 1024 dwords
__global__ void init_flags(unsigned int* __restrict__ p) {
    p[blockIdx.x * 256 + threadIdx.x] = 0;
}

// ---------- build X = concat(embed_table[slot_ids], value_embeds) as bf16 [16384][1024] ----------
__global__ void build_x(const int* __restrict__ slot_ids,
                        const float* __restrict__ value_embeds,
                        const float* __restrict__ embed_table,
                        unsigned short* __restrict__ X) {
    int r = blockIdx.x;           // r = b*64 + s
    int t = threadIdx.x;          // 256 threads
    int id = slot_ids[r];
    X[(long)r * 1024 + t] = f2bf(embed_table[id * 256 + t]);
#pragma unroll
    for (int i = 0; i < 3; i++) {
        int c = t + i * 256;
        X[(long)r * 1024 + 256 + c] = f2bf(value_embeds[(long)r * 768 + c]);
    }
}

// ---------- bf16 MFMA GEMM: C[M][N] = A[M][K] * Bt[N][K]^T ----------
// Round-5 register-staged body (verified across 300+ launches). The round-9
// global_load_lds staging caused replay-dependent corruption (first launch OK,
// all post-capture launches absmax 1.95) with no identifiable mechanism -> shelved
// per rigor discipline. Kept from round 9: 1D grid + bijective XCD swizzle
// (pure index permutation; per-XCD A-panel working set = 16 M-panels = 4MB = one L2).
// EPI=0: plain f32 store C[row*N+col]
// EPI=1: scatter gi packed for gru_rec consumers:
//   [d][s][bg 8][cb 16][wave 4][g 3][lane 64][r 4] f32
template <int EPI>
__global__ __launch_bounds__(256) void gemm_bt(const unsigned short* __restrict__ A,
                                               const unsigned short* __restrict__ Bt,
                                               float* __restrict__ C,
                                               int M, int N, int K) {
    const int LDT = 72;
    __shared__ unsigned short As[128 * 72];
    __shared__ unsigned short Bs[128 * 72];
    int tid = threadIdx.x;
    int lane = tid & 63;
    int wave = tid >> 6;
    // XCD-aware bijective swizzle (gridDim.x % 8 == 0 for both launches)
    int cpx = gridDim.x >> 3;
    int swz = (blockIdx.x & 7) * cpx + (blockIdx.x >> 3);
    int nbx = N >> 7;
    int gm0 = (swz / nbx) * 128;
    int gn0 = (swz % nbx) * 128;
    int wm0 = (wave >> 1) * 64;
    int wn0 = (wave & 1) * 64;
    int q = lane >> 4;
    int l16 = lane & 15;

    v4f acc[4][4];
#pragma unroll
    for (int i = 0; i < 4; i++)
#pragma unroll
        for (int j = 0; j < 4; j++) acc[i][j] = v4f{0.f, 0.f, 0.f, 0.f};

    for (int k0 = 0; k0 < K; k0 += 64) {
#pragma unroll
        for (int l = tid; l < 1024; l += 256) {
            int row = l >> 3;
            int col = (l & 7) * 8;
            *(v8s*)&As[row * LDT + col] = *(const v8s*)&A[(long)(gm0 + row) * K + k0 + col];
            *(v8s*)&Bs[row * LDT + col] = *(const v8s*)&Bt[(long)(gn0 + row) * K + k0 + col];
        }
        __syncthreads();
#pragma unroll
        for (int kf = 0; kf < 2; kf++) {
            v8s af[4], bfr[4];
#pragma unroll
            for (int mi = 0; mi < 4; mi++)
                af[mi] = *(const v8s*)&As[(wm0 + mi * 16 + l16) * LDT + kf * 32 + q * 8];
#pragma unroll
            for (int ni = 0; ni < 4; ni++)
                bfr[ni] = *(const v8s*)&Bs[(wn0 + ni * 16 + l16) * LDT + kf * 32 + q * 8];
#pragma unroll
            for (int mi = 0; mi < 4; mi++)
#pragma unroll
                for (int ni = 0; ni < 4; ni++)
                    acc[mi][ni] = __builtin_amdgcn_mfma_f32_16x16x32_bf16(af[mi], bfr[ni], acc[mi][ni], 0, 0, 0);
        }
        __syncthreads();
    }

#pragma unroll
    for (int mi = 0; mi < 4; mi++)
#pragma unroll
        for (int ni = 0; ni < 4; ni++) {
            int col = gn0 + wn0 + ni * 16 + l16;
#pragma unroll
            for (int r = 0; r < 4; r++) {
                int row = gm0 + wm0 + mi * 16 + q * 4 + r;
                float v = acc[mi][ni][r];
                if (EPI == 0) {
                    C[(long)row * N + col] = v;
                } else {
                    int dd = (col >= 1536) ? 1 : 0;
                    int gcol = col - dd * 1536;
                    int g = gcol >> 9;
                    int jj = gcol & 511;
                    int cb = jj >> 5;
                    int jc = jj & 31;
                    int jhc = jc >> 4;
                    int l16c = jc & 15;
                    int b = row >> 6, s = row & 63;
                    int bg = b >> 5, brow = b & 31;
                    int rgc = brow >> 4, m = brow & 15;
                    int qc = m >> 2, rc = m & 3;
                    int wv = rgc * 2 + jhc;
                    long idx = (((((long)(dd * 64 + s) * 8 + bg) * 16 + cb) * 4 + wv) * 3 + g) * 256 +
                               (qc * 16 + l16c) * 4 + rc;
                    C[idx] = v;
                }
            }
        }
}

// ---------- GRU recurrence: W in AGPRs, per-wave flags, no LDS, no barriers ----------
// (VERBATIM round-5 kernel — best verified configuration, 443us. Abandoned sync lines:
// sc0 = 2 hangs (not reliably cross-CU coherent); tag-in-data = intermittent corruption,
// root cause unproven; global_load_lds in gemm = replay-dependent corruption, unproven.
// Agent-scope sc1 flag protocol is the proven floor: ~7us/step MALL hop latency.)
// 256 blocks x 256 threads (1 block/CU). blk = d*128 + bg*16 + cb.
// team = (d,bg): 16 blocks x 4 waves = 64 producer waves splitting 512 h-cols.
// W_hh held in AGPRs via "+a" pins + "a"-constraint MFMA B operand (cannot be
// demoted/remat'd). Sync: sc1 data stores -> vmcnt(0) -> relaxed per-wave flag;
// consumer polls 64 flags then 16-in-flight early-clobber asm loads.
__global__ __launch_bounds__(256, 1) void gru_rec(const float* __restrict__ gi,           // packed, see EPI=1
                                                  const unsigned short* __restrict__ Wpk, // [2][96][16][64][8]
                                                  const float* __restrict__ bih_f,
                                                  const float* __restrict__ bhh_f,
                                                  const float* __restrict__ bih_b,
                                                  const float* __restrict__ bhh_b,
                                                  unsigned short* __restrict__ hout,      // [256][64][1024]
                                                  unsigned int* __restrict__ hshd,        // [16][2][8192] dwords
                                                  unsigned int* __restrict__ flags) {     // [16][64]
    int tid = threadIdx.x;
    int lane = tid & 63;
    int wave = tid >> 6;          // 0..3
    int q = lane >> 4, l16 = lane & 15;
    int blk = blockIdx.x;
    int d = blk >> 7;
    int bg = (blk >> 4) & 7;
    int cb = blk & 15;
    int team = d * 8 + bg;
    int rg = wave >> 1, jh = wave & 1;
    int j = cb * 32 + jh * 16 + l16;   // owned h-col

    // W_hh B-fragments (step-invariant): 3 gates x 16 kf, each 4 regs -> 192 AGPRs.
    v4u wA[3][16];
#pragma unroll
    for (int g = 0; g < 3; g++) {
        const unsigned short* wp = Wpk + ((long)d * 96 + (g * 32 + cb * 2 + jh)) * 8192;
#pragma unroll
        for (int kf = 0; kf < 16; kf++) {
            v8s w = *(const v8s*)&wp[(kf * 64 + lane) * 8];
            wA[g][kf] = __builtin_bit_cast(v4u, w);
            asm volatile("" : "+a"(wA[g][kf]));
        }
    }

    float bi[3], bh[3];
    {
        const float* bihp = d ? bih_b : bih_f;
        const float* bhhp = d ? bhh_b : bhh_f;
#pragma unroll
        for (int g = 0; g < 3; g++) {
            bi[g] = bihp[g * 512 + j];
            bh[g] = bhhp[g * 512 + j];
        }
    }
    float hreg[4] = {0.f, 0.f, 0.f, 0.f};

    unsigned int* myflags = flags + team * 64;
    unsigned int* hsteam = hshd + (long)team * 2 * 8192;

    // prefetch gi for t = 0
    v4f gir[3];
    {
        int s0 = d ? 63 : 0;
        const float* gp = gi + (((((long)(d * 64 + s0)) * 8 + bg) * 16 + cb) * 4 + wave) * 768 + lane * 4;
#pragma unroll
        for (int g = 0; g < 3; g++) gir[g] = __builtin_nontemporal_load((const v4f*)(gp + g * 256));
    }

    for (int t = 0; t < 64; t++) {
        int s = d ? (63 - t) : t;

        v4f acc[3];
#pragma unroll
        for (int g = 0; g < 3; g++) acc[g] = v4f{0.f, 0.f, 0.f, 0.f};

        if (t > 0) {
            // per-wave poll: all 64 producer-wave flags of this team must reach t
            while (__hip_atomic_load(&myflags[lane], __ATOMIC_RELAXED, __HIP_MEMORY_SCOPE_AGENT) <
                   (unsigned)t)
                __builtin_amdgcn_s_sleep(1);
            __builtin_amdgcn_sched_barrier(0);

            // h_{t-1} A-fragments from the exchange buffer (row-major [32][512] bf16).
            // 16 device-scope (sc1) 16B loads off one base, all in flight. EARLY-CLOBBER
            // outputs (round 2's crash: without & the dst may alias the address pair).
            const char* hb = (const char*)hsteam + ((t + 1) & 1) * 32768 +
                             (rg * 16 + l16) * 1024 + q * 16;
            v4u a0, a1, a2, a3, a4, a5, a6, a7, a8, a9, a10, a11, a12, a13, a14, a15;
            asm volatile(
                "global_load_dwordx4 %0, %16, off sc1\n\t"
                "global_load_dwordx4 %1, %16, off offset:64 sc1\n\t"
                "global_load_dwordx4 %2, %16, off offset:128 sc1\n\t"
                "global_load_dwordx4 %3, %16, off offset:192 sc1\n\t"
                "global_load_dwordx4 %4, %16, off offset:256 sc1\n\t"
                "global_load_dwordx4 %5, %16, off offset:320 sc1\n\t"
                "global_load_dwordx4 %6, %16, off offset:384 sc1\n\t"
                "global_load_dwordx4 %7, %16, off offset:448 sc1\n\t"
                "global_load_dwordx4 %8, %16, off offset:512 sc1\n\t"
                "global_load_dwordx4 %9, %16, off offset:576 sc1\n\t"
                "global_load_dwordx4 %10, %16, off offset:640 sc1\n\t"
                "global_load_dwordx4 %11, %16, off offset:704 sc1\n\t"
                "global_load_dwordx4 %12, %16, off offset:768 sc1\n\t"
                "global_load_dwordx4 %13, %16, off offset:832 sc1\n\t"
                "global_load_dwordx4 %14, %16, off offset:896 sc1\n\t"
                "global_load_dwordx4 %15, %16, off offset:960 sc1"
                : "=&v"(a0), "=&v"(a1), "=&v"(a2), "=&v"(a3), "=&v"(a4), "=&v"(a5), "=&v"(a6),
                  "=&v"(a7), "=&v"(a8), "=&v"(a9), "=&v"(a10), "=&v"(a11), "=&v"(a12), "=&v"(a13),
                  "=&v"(a14), "=&v"(a15)
                : "v"(hb)
                : "memory");
            asm volatile("s_waitcnt vmcnt(0)" ::: "memory");
            __builtin_amdgcn_sched_barrier(0);

            v4u af[16];
            af[0] = a0;  af[1] = a1;  af[2] = a2;  af[3] = a3;
            af[4] = a4;  af[5] = a5;  af[6] = a6;  af[7] = a7;
            af[8] = a8;  af[9] = a9;  af[10] = a10; af[11] = a11;
            af[12] = a12; af[13] = a13; af[14] = a14; af[15] = a15;

            // 48 MFMA, B operand sourced DIRECTLY from AGPRs (no per-use reload possible).
#pragma unroll
            for (int kf = 0; kf < 16; kf++)
#pragma unroll
                for (int g = 0; g < 3; g++)
                    asm("v_mfma_f32_16x16x32_bf16 %0, %1, %2, %0"
                        : "+v"(acc[g])
                        : "v"(af[kf]), "a"(wA[g][kf]));
        }

        // combine gates, update h, publish exchange slice (sc1 dword stores)
        unsigned int* dst = hsteam + (t & 1) * 8192;
        unsigned short hv[4];
#pragma unroll
        for (int r = 0; r < 4; r++) {
            float rr = sigm(gir[0][r] + bi[0] + acc[0][r] + bh[0]);
            float zz = sigm(gir[1][r] + bi[1] + acc[1][r] + bh[1]);
            float nn = tanh_fast(gir[2][r] + bi[2] + rr * (acc[2][r] + bh[2]));
            float hn = (1.f - zz) * nn + zz * hreg[r];
            hreg[r] = hn;
            hv[r] = f2bf(hn);
            float pv = __shfl_xor(hn, 1);
            if ((l16 & 1) == 0) {
                unsigned int pack = (unsigned int)hv[r] | ((unsigned int)f2bf(pv) << 16);
                int row = rg * 16 + q * 4 + r;
                __hip_atomic_store(&dst[row * 256 + (j >> 1)], pack, __ATOMIC_RELAXED,
                                   __HIP_MEMORY_SCOPE_AGENT);
            }
        }

        // drain this wave's sc1 stores to the coherence point, then publish per-wave flag
        asm volatile("s_waitcnt vmcnt(0)" ::: "memory");
        if (lane == 0)
            __hip_atomic_store(&myflags[cb * 4 + wave], (unsigned)(t + 1), __ATOMIC_RELAXED,
                               __HIP_MEMORY_SCOPE_AGENT);

        // off the critical path: final output + next-step gi prefetch
#pragma unroll
        for (int r = 0; r < 4; r++) {
            int row = rg * 16 + q * 4 + r;
            hout[((long)(bg * 32 + row) * 64 + s) * 1024 + d * 512 + j] = hv[r];
        }
        if (t < 63) {
            int sn = d ? (62 - t) : (t + 1);
            const float* gp =
                gi + (((((long)(d * 64 + sn)) * 8 + bg) * 16 + cb) * 4 + wave) * 768 + lane * 4;
#pragma unroll
            for (int g = 0; g < 3; g++) gir[g] = __builtin_nontemporal_load((const v4f*)(gp + g * 256));
        }
    }
}

extern "C" void kernel_launch(void* const* d_in, const int* in_sizes, int n_in,
                              void* d_out, int out_size, void* d_ws, size_t ws_size,
                              hipStream_t stream) {
    const int* slot_ids = (const int*)d_in[0];
    const float* value_embeds = (const float*)d_in[1];
    const float* embed_table = (const float*)d_in[2];
    const float* W_ih_f = (const float*)d_in[3];
    const float* W_hh_f = (const float*)d_in[4];
    const float* b_ih_f = (const float*)d_in[5];
    const float* b_hh_f = (const float*)d_in[6];
    const float* W_ih_b = (const float*)d_in[7];
    const float* W_hh_b = (const float*)d_in[8];
    const float* b_ih_b = (const float*)d_in[9];
    const float* b_hh_b = (const float*)d_in[10];
    const float* W_proj = (const float*)d_in[11];
    float* out = (float*)d_out;
    char* ws = (char*)d_ws;

    // workspace layout (bytes)
    unsigned short* X = (unsigned short*)(ws + 0);              // 16384x1024 bf16 = 33,554,432
    float* gi = (float*)(ws + 33554432);                        // 50,331,648 f32 = 201,326,592
    unsigned short* Wstk = (unsigned short*)(ws + 234881024);   // 3072x1024 bf16 = 6,291,456 (dead after gemm1)
    unsigned short* Wpk = (unsigned short*)(ws + 241172480);    // 2x96x16x64x8 bf16 = 3,145,728
    unsigned short* Wp = (unsigned short*)(ws + 244318208);     // 512x1024 bf16 = 1,048,576
    unsigned short* hout = X;  // alias: X dead after gemm1
    // h-share + flags alias the (dead-after-gemm1) Wstk region
    unsigned int* hshd = (unsigned int*)Wstk;                   // 16*2*8192 dwords = 1 MB
    unsigned int* flags = (unsigned int*)(ws + 234881024 + 1048576);  // 1024 dwords

    cvt_bf16<<<6144, 256, 0, stream>>>(W_ih_f, Wstk, 1536 * 1024);
    cvt_bf16<<<6144, 256, 0, stream>>>(W_ih_b, Wstk + 1536 * 1024, 1536 * 1024);
    repack_whh<<<3072, 256, 0, stream>>>(W_hh_f, Wpk);
    repack_whh<<<3072, 256, 0, stream>>>(W_hh_b, Wpk + 786432);
    cvt_bf16<<<2048, 256, 0, stream>>>(W_proj, Wp, 512 * 1024);
    build_x<<<16384, 256, 0, stream>>>(slot_ids, value_embeds, embed_table, X);

    // gi = X @ [Wih_f; Wih_b]^T  (M=16384, N=3072, K=1024), packed epilogue
    // 1D grid (24*128 = 3072, %8==0 for the XCD swizzle)
    gemm_bt<1><<<3072, 256, 0, stream>>>(X, Wstk, gi, 16384, 3072, 1024);

    // zero flags (after gemm1: aliases Wstk region)
    init_flags<<<4, 256, 0, stream>>>(flags);

    // recurrence: 256 co-resident blocks, AGPR-resident W, per-wave flag sync
    gru_rec<<<256, 256, 0, stream>>>(gi, Wpk, b_ih_f, b_hh_f, b_ih_b, b_hh_b, hout, hshd, flags);

    // out = hcat @ W_proj^T   (M=16384, N=512, K=1024); 1D grid (4*128 = 512, %8==0)
    gemm_bt<0><<<512, 256, 0, stream>>>(hout, Wp, out, 16384, 512, 1024);
}